// Round 2
// baseline (539.290 us; speedup 1.0000x reference)
//
#include <hip/hip_runtime.h>

// ProvidenceLSTM: fused LSTM (T=512,B=2048,I=24,H=20) + masked heads.
// One wave (64 lanes) per batch element; lane l<40 owns gate rows l and l+40
// (i,f,g,o ordering) with W held in registers across all timesteps.
// x(t)/h(t) are wave-uniform: x via broadcast global loads, h via LDS broadcast.
// Early exit at t = len[b]; tail filled with exp(b_a)/softplus(b_b) constants.

constexpr int T_ = 512;
constexpr int B_ = 2048;
constexpr int I_ = 24;
constexpr int H_ = 20;

__device__ __forceinline__ float sigm(float x) {
  return __fdividef(1.0f, 1.0f + __expf(-x));
}
__device__ __forceinline__ float tanh_fast(float x) {
  // tanh(x) = 1 - 2/(e^(2x)+1)
  return 1.0f - __fdividef(2.0f, 1.0f + __expf(2.0f * x));
}
__device__ __forceinline__ float softplus_fast(float x) {
  // inputs bounded ~|x|<6 here; no overflow risk
  return __logf(1.0f + __expf(x));
}

__device__ __forceinline__ void load24(const float* __restrict__ p, float* dst) {
  const float4* q = (const float4*)p;
  float4 v0 = q[0], v1 = q[1], v2 = q[2], v3 = q[3], v4 = q[4], v5 = q[5];
  dst[0] = v0.x;  dst[1] = v0.y;  dst[2] = v0.z;  dst[3] = v0.w;
  dst[4] = v1.x;  dst[5] = v1.y;  dst[6] = v1.z;  dst[7] = v1.w;
  dst[8] = v2.x;  dst[9] = v2.y;  dst[10] = v2.z; dst[11] = v2.w;
  dst[12] = v3.x; dst[13] = v3.y; dst[14] = v3.z; dst[15] = v3.w;
  dst[16] = v4.x; dst[17] = v4.y; dst[18] = v4.z; dst[19] = v4.w;
  dst[20] = v5.x; dst[21] = v5.y; dst[22] = v5.z; dst[23] = v5.w;
}

__global__ __launch_bounds__(256, 2)
void lstm_fused(const float* __restrict__ x,      // [T,B,I]
                const int* __restrict__ lens,     // [B]
                const float* __restrict__ W_ih,   // [80,24]
                const float* __restrict__ W_hh,   // [80,20]
                const float* __restrict__ b_ih,   // [80]
                const float* __restrict__ b_hh,   // [80]
                const float* __restrict__ W_a,    // [1,20]
                const float* __restrict__ b_a,    // [1]
                const float* __restrict__ W_b,    // [1,20]
                const float* __restrict__ b_b,    // [1]
                float* __restrict__ out)          // alpha[T*B] ++ beta[T*B]
{
  const int lane = threadIdx.x & 63;
  const int wid  = threadIdx.x >> 6;
  const int b    = (blockIdx.x << 2) + wid;

  __shared__ float hsm[4][32];   // per-wave h broadcast buffer

  const int len = lens[b];
  const bool own = lane < 40;          // lanes 0..39 own 2 gate rows each
  const int g0 = own ? lane : 0;       // row g0: i[j] (j<20) or f[j] (20<=l<40)
  const int g1 = g0 + 40;              // row g1: g[j]          or o[j]

  // --- weights pinned in registers for the whole sequence ---
  float Wx0[I_], Wx1[I_], Wh0[H_], Wh1[H_];
  #pragma unroll
  for (int k = 0; k < I_; ++k) {
    Wx0[k] = own ? W_ih[g0 * I_ + k] : 0.0f;
    Wx1[k] = own ? W_ih[g1 * I_ + k] : 0.0f;
  }
  #pragma unroll
  for (int k = 0; k < H_; ++k) {
    Wh0[k] = own ? W_hh[g0 * H_ + k] : 0.0f;
    Wh1[k] = own ? W_hh[g1 * H_ + k] : 0.0f;
  }
  const float bias0 = own ? b_ih[g0] + b_hh[g0] : 0.0f;
  const float bias1 = own ? b_ih[g1] + b_hh[g1] : 0.0f;

  const float wa = (lane < H_) ? W_a[lane] : 0.0f;
  const float wb = (lane < H_) ? W_b[lane] : 0.0f;
  const float ba = b_a[0], bb = b_b[0];

  float c = 0.0f, h = 0.0f;            // valid on lanes 0..19 (unit j = lane)
  float hb[H_];                        // broadcast copy of h[0..19], all lanes
  #pragma unroll
  for (int k = 0; k < H_; ++k) hb[k] = 0.0f;

  const float* xp = x + (size_t)b * I_;       // x[t,b,:] = xp + t*B*I
  const size_t TB = (size_t)T_ * B_;

  // --- prologue: acc for t=0 = bias + x(0)·W_ih ---
  float acc0 = bias0, acc1 = bias1;
  {
    float xf0[I_];
    load24(xp, xf0);
    #pragma unroll
    for (int k = 0; k < I_; ++k) { acc0 += Wx0[k] * xf0[k]; acc1 += Wx1[k] * xf0[k]; }
  }

  #pragma unroll 1
  for (int t = 0; t < len; ++t) {
    // (a) issue x(t+1) loads early (wave-uniform branch)
    float xf[I_];
    const bool pf = (t + 1 < len);
    if (pf) load24(xp + (size_t)(t + 1) * (B_ * I_), xf);

    // (b) h-dependent FMAs (2 partial sums per gate to relax dep-latency)
    float s0a = 0.0f, s0b = 0.0f, s1a = 0.0f, s1b = 0.0f;
    #pragma unroll
    for (int k = 0; k < H_; k += 2) {
      s0a += Wh0[k] * hb[k];     s0b += Wh0[k + 1] * hb[k + 1];
      s1a += Wh1[k] * hb[k];     s1b += Wh1[k + 1] * hb[k + 1];
    }
    const float a0 = acc0 + s0a + s0b;   // i[j] (lane<20) / f[j] (lane 20..39)
    const float a1 = acc1 + s1a + s1b;   // g[j] (lane<20) / o[j] (lane 20..39)

    // (c) gather f,o from lane j+20; update c,h on lanes 0..19
    const float f_ = __shfl(a0, lane + 20, 64);
    const float o_ = __shfl(a1, lane + 20, 64);
    const float si = sigm(a0);
    const float tg = tanh_fast(a1);
    const float sf = sigm(f_);
    const float so = sigm(o_);
    c = sf * c + si * tg;
    h = so * tanh_fast(c);

    // (d) heads: alpha = exp(h·W_a + b_a), beta = softplus(h·W_b + b_b)
    float pa = (lane < H_) ? h * wa : 0.0f;
    float pb = (lane < H_) ? h * wb : 0.0f;
    #pragma unroll
    for (int m = 16; m; m >>= 1) {
      pa += __shfl_xor(pa, m, 32);
      pb += __shfl_xor(pb, m, 32);
    }
    if (lane == 0) {
      out[(size_t)t * B_ + b]      = __expf(pa + ba);
      out[TB + (size_t)t * B_ + b] = softplus_fast(pb + bb);
    }

    // (e) broadcast new h via LDS (single wave: in-order DS + lgkmcnt suffices)
    if (lane < H_) hsm[wid][lane] = h;
    asm volatile("s_waitcnt lgkmcnt(0)" ::: "memory");
    {
      const float4* hp = (const float4*)(&hsm[wid][0]);
      #pragma unroll
      for (int q5 = 0; q5 < 5; ++q5) {
        const float4 h4 = hp[q5];
        hb[4 * q5 + 0] = h4.x; hb[4 * q5 + 1] = h4.y;
        hb[4 * q5 + 2] = h4.z; hb[4 * q5 + 3] = h4.w;
      }
    }

    // (f) pre-accumulate bias + x(t+1)·W_ih for the next step
    if (pf) {
      float n0 = bias0, n1 = bias1;
      #pragma unroll
      for (int k = 0; k < I_; ++k) { n0 += Wx0[k] * xf[k]; n1 += Wx1[k] * xf[k]; }
      acc0 = n0; acc1 = n1;
    }
  }

  // --- tail: t >= len ⇒ h masked to 0 ⇒ constant outputs ---
  const float apad = __expf(ba);
  const float bpad = softplus_fast(bb);
  for (int t = len + lane; t < T_; t += 64) {
    out[(size_t)t * B_ + b]      = apad;
    out[TB + (size_t)t * B_ + b] = bpad;
  }
}

extern "C" void kernel_launch(void* const* d_in, const int* in_sizes, int n_in,
                              void* d_out, int out_size, void* d_ws, size_t ws_size,
                              hipStream_t stream) {
  (void)in_sizes; (void)n_in; (void)out_size; (void)d_ws; (void)ws_size;
  lstm_fused<<<dim3(B_ / 4), dim3(256), 0, stream>>>(
      (const float*)d_in[0], (const int*)d_in[1],
      (const float*)d_in[2], (const float*)d_in[3],
      (const float*)d_in[4], (const float*)d_in[5],
      (const float*)d_in[6], (const float*)d_in[7],
      (const float*)d_in[8], (const float*)d_in[9],
      (float*)d_out);
}

// Round 3
// 484.852 us; speedup vs baseline: 1.1123x; 1.1123x over previous
//
#include <hip/hip_runtime.h>

// ProvidenceLSTM fused: k1 = recurrence only (one wave per batch element,
// lanes 0..19 own i/g rows, lanes 32..51 own f/o rows, single __shfl_xor(32)
// per step, h broadcast via v_readlane -> SGPR, packed-fp32 dot products,
// h written to d_ws). k2 = massively parallel heads (alpha/beta) + pad tail.
// Fallback MODE 1 (ws too small): heads computed in-lane from SGPR h.

typedef float f2 __attribute__((ext_vector_type(2)));

constexpr int T_ = 512;
constexpr int B_ = 2048;
constexpr int I_ = 24;
constexpr int H_ = 20;
constexpr size_t TB_ = (size_t)T_ * B_;
constexpr size_t HS_BYTES = TB_ * H_ * sizeof(float);

__device__ __forceinline__ float sigm(float x) {
  return __fdividef(1.0f, 1.0f + __expf(-x));
}
__device__ __forceinline__ float tanh_fast(float x) {
  return 1.0f - __fdividef(2.0f, 1.0f + __expf(2.0f * x));
}
__device__ __forceinline__ float softplus_fast(float x) {
  return __logf(1.0f + __expf(x));
}
__device__ __forceinline__ float rdlane(float v, int l) {
  return __int_as_float(__builtin_amdgcn_readlane(__float_as_int(v), l));
}
__device__ __forceinline__ f2 pkfma(f2 a, float s, f2 c) {
  return __builtin_elementwise_fma(a, (f2){s, s}, c);
}

// MODE 0: write hs to d_ws, heads done by heads_k.
// MODE 1: standalone (no workspace): in-lane heads + tail fill.
template <int MODE>
__global__ __launch_bounds__(64, 2)
void lstm_rec(const float* __restrict__ x,      // [T,B,I]
              const int* __restrict__ lens,     // [B]
              const float* __restrict__ W_ih,   // [80,24]
              const float* __restrict__ W_hh,   // [80,20]
              const float* __restrict__ b_ih,   // [80]
              const float* __restrict__ b_hh,   // [80]
              const float* __restrict__ W_a, const float* __restrict__ b_a,
              const float* __restrict__ W_b, const float* __restrict__ b_b,
              float* __restrict__ hs,           // [T,B,H] (MODE 0)
              float* __restrict__ out)          // alpha[T*B] ++ beta[T*B]
{
  const int lane = threadIdx.x;                 // 0..63
  const int b = blockIdx.x;
  const int len = lens[b];

  const bool grpA = lane < H_;                      // i,g rows, unit j=lane
  const bool grpB = (lane >= 32) && (lane < 32 + H_); // f,o rows, j=lane-32
  const bool own = grpA || grpB;
  const int j = grpA ? lane : (grpB ? (lane - 32) : 0);
  const int g0 = grpA ? j : (H_ + j);             // i[j] (A) / f[j] (B)
  const int g1 = g0 + 2 * H_;                     // g[j] (A) / o[j] (B)

  // --- weights pinned in registers (packed (g0,g1) pairs) ---
  f2 Wx[I_], Wh[H_];
  #pragma unroll
  for (int k = 0; k < I_; ++k) {
    f2 w = { W_ih[g0 * I_ + k], W_ih[g1 * I_ + k] };
    Wx[k] = own ? w : (f2){0.0f, 0.0f};
  }
  #pragma unroll
  for (int k = 0; k < H_; ++k) {
    f2 w = { W_hh[g0 * H_ + k], W_hh[g1 * H_ + k] };
    Wh[k] = own ? w : (f2){0.0f, 0.0f};
  }
  f2 bias = { b_ih[g0] + b_hh[g0], b_ih[g1] + b_hh[g1] };
  bias = own ? bias : (f2){0.0f, 0.0f};

  f2 wab[H_];
  float ba = 0.0f, bb = 0.0f;
  if constexpr (MODE == 1) {
    #pragma unroll
    for (int k = 0; k < H_; ++k) wab[k] = (f2){ W_a[k], W_b[k] };
    ba = b_a[0]; bb = b_b[0];
  }

  float hk[H_];
  #pragma unroll
  for (int k = 0; k < H_; ++k) hk[k] = 0.0f;
  float c = 0.0f, h = 0.0f;

  const float* xp = x + (size_t)b * I_;           // x[t,b,:] = xp + t*B*I

  // --- prologue: acc = bias + x(0)·W_ih ---
  f2 acc = bias;
  #pragma unroll
  for (int k = 0; k < I_; ++k) acc = pkfma(Wx[k], xp[k], acc);

  #pragma unroll 1
  for (int t = 0; t < len; ++t) {
    // (a) prefetch x(t+1)
    float xf[I_];
    const bool pf = (t + 1 < len);
    if (pf) {
      const float4* q = (const float4*)(xp + (size_t)(t + 1) * (B_ * I_));
      float4 v0 = q[0], v1 = q[1], v2 = q[2], v3 = q[3], v4 = q[4], v5 = q[5];
      xf[0]=v0.x;  xf[1]=v0.y;  xf[2]=v0.z;  xf[3]=v0.w;
      xf[4]=v1.x;  xf[5]=v1.y;  xf[6]=v1.z;  xf[7]=v1.w;
      xf[8]=v2.x;  xf[9]=v2.y;  xf[10]=v2.z; xf[11]=v2.w;
      xf[12]=v3.x; xf[13]=v3.y; xf[14]=v3.z; xf[15]=v3.w;
      xf[16]=v4.x; xf[17]=v4.y; xf[18]=v4.z; xf[19]=v4.w;
      xf[20]=v5.x; xf[21]=v5.y; xf[22]=v5.z; xf[23]=v5.w;
    }

    // (b) a = acc + W_hh·h   (packed, 2 partial chains, SGPR h operands)
    f2 sA = (f2){0.0f, 0.0f}, sB = (f2){0.0f, 0.0f};
    #pragma unroll
    for (int k = 0; k < H_; k += 2) {
      sA = pkfma(Wh[k],     hk[k],     sA);
      sB = pkfma(Wh[k + 1], hk[k + 1], sB);
    }
    const f2 a = acc + sA + sB;   // (i,g) on A lanes; (f,o) on B lanes

    // (c) branch-free nonlinearities:
    //     A: si=sigm(i), v=tanh(g)=2*sigm(2g)-1 ; B: sf=sigm(f), v=sigm(o)
    const float u = sigm(a.x);
    const float yy = grpA ? (a.y + a.y) : a.y;
    const float s2 = sigm(yy);
    const float v = grpA ? fmaf(2.0f, s2, -1.0f) : s2;
    const float p = u * v;                 // A: si*tanh(g)
    const float p_ = __shfl_xor(p, 32, 64);  // B lanes receive from lane-32
    c = fmaf(u, c, p_);                    // B: sigm(f)*c + si*tanh(g)
    const float tc = tanh_fast(c);
    h = v * tc;                            // B: sigm(o)*tanh(c)

    if constexpr (MODE == 0) {
      if (grpB) hs[((size_t)t * B_ + b) * H_ + j] = h;   // 80B contiguous
    }

    // (d) broadcast h via readlane -> SGPRs (no LDS round-trip)
    #pragma unroll
    for (int k = 0; k < H_; ++k) hk[k] = rdlane(h, 32 + k);

    if constexpr (MODE == 1) {
      f2 pa = (f2){0.0f, 0.0f}, pb = (f2){0.0f, 0.0f};
      #pragma unroll
      for (int k = 0; k < H_; k += 2) {
        pa = pkfma(wab[k],     hk[k],     pa);
        pb = pkfma(wab[k + 1], hk[k + 1], pb);
      }
      const f2 pp = pa + pb;               // (dot_a, dot_b), wave-uniform
      if (lane == 0) {
        out[(size_t)t * B_ + b]       = __expf(pp.x + ba);
        out[TB_ + (size_t)t * B_ + b] = softplus_fast(pp.y + bb);
      }
    }

    // (e) pre-accumulate bias + x(t+1)·W_ih
    if (pf) {
      f2 na = bias;
      #pragma unroll
      for (int k = 0; k < I_; ++k) na = pkfma(Wx[k], xf[k], na);
      acc = na;
    }
  }

  if constexpr (MODE == 1) {
    const float apad = __expf(ba);
    const float bpad = softplus_fast(bb);
    for (int t = len + lane; t < T_; t += 64) {
      out[(size_t)t * B_ + b]       = apad;
      out[TB_ + (size_t)t * B_ + b] = bpad;
    }
  }
}

// k2: heads for all (t,b); constants for t >= len[b]. Memory-bound.
__global__ __launch_bounds__(256)
void heads_k(const float* __restrict__ hs, const int* __restrict__ lens,
             const float* __restrict__ W_a, const float* __restrict__ b_a,
             const float* __restrict__ W_b, const float* __restrict__ b_b,
             float* __restrict__ out)
{
  const size_t n = (size_t)blockIdx.x * 256 + threadIdx.x;   // = t*B + b
  const int b = (int)(n & (size_t)(B_ - 1));
  const int t = (int)(n >> 11);                              // B = 2^11
  const int len = lens[b];
  float da = b_a[0], db = b_b[0];
  if (t < len) {
    const float* hp = hs + n * H_;
    #pragma unroll
    for (int k = 0; k < H_; k += 4) {
      const float4 h4 = *(const float4*)(hp + k);
      da += h4.x * W_a[k]     + h4.y * W_a[k + 1]
          + h4.z * W_a[k + 2] + h4.w * W_a[k + 3];
      db += h4.x * W_b[k]     + h4.y * W_b[k + 1]
          + h4.z * W_b[k + 2] + h4.w * W_b[k + 3];
    }
  }
  out[n]       = __expf(da);
  out[TB_ + n] = softplus_fast(db);
}

extern "C" void kernel_launch(void* const* d_in, const int* in_sizes, int n_in,
                              void* d_out, int out_size, void* d_ws, size_t ws_size,
                              hipStream_t stream) {
  (void)in_sizes; (void)n_in; (void)out_size;
  const float* x    = (const float*)d_in[0];
  const int*   lens = (const int*)d_in[1];
  const float* W_ih = (const float*)d_in[2];
  const float* W_hh = (const float*)d_in[3];
  const float* b_ih = (const float*)d_in[4];
  const float* b_hh = (const float*)d_in[5];
  const float* W_a  = (const float*)d_in[6];
  const float* b_a  = (const float*)d_in[7];
  const float* W_b  = (const float*)d_in[8];
  const float* b_b  = (const float*)d_in[9];
  float* out = (float*)d_out;

  if (ws_size >= HS_BYTES) {
    float* hs = (float*)d_ws;
    lstm_rec<0><<<dim3(B_), dim3(64), 0, stream>>>(
        x, lens, W_ih, W_hh, b_ih, b_hh, W_a, b_a, W_b, b_b, hs, out);
    heads_k<<<dim3((unsigned)(TB_ / 256)), dim3(256), 0, stream>>>(
        hs, lens, W_a, b_a, W_b, b_b, out);
  } else {
    lstm_rec<1><<<dim3(B_), dim3(64), 0, stream>>>(
        x, lens, W_ih, W_hh, b_ih, b_hh, W_a, b_a, W_b, b_b, nullptr, out);
  }
}